// Round 5
// baseline (366.930 us; speedup 1.0000x reference)
//
#include <hip/hip_runtime.h>
#include <stdint.h>

typedef __bf16 bf16;
typedef __bf16 bf16x8 __attribute__((ext_vector_type(8)));
typedef float  f32x4  __attribute__((ext_vector_type(4)));

#if __has_builtin(__builtin_amdgcn_exp2f)
#define EXP2F(x) __builtin_amdgcn_exp2f(x)
#else
#define EXP2F(x) exp2f(x)
#endif

constexpr int Bn = 8192, Sn = 256, Rn = 8192;
constexpr int BM = 64, BK = 32, KP = 8;
constexpr int KLEN = Rn / KP;  // 1024
constexpr int NC = KLEN / BK;  // 32 chunks (even -> clean 2x unroll)

// ---------- prep: params + perb + inc->bf16 + zero(out) ----------
__global__ __launch_bounds__(256) void prep_all(
    const float* __restrict__ inc, bf16* __restrict__ incb, float* __restrict__ out,
    const float* __restrict__ alpha, const float* __restrict__ beta,
    const float* __restrict__ gam, const int* __restrict__ rm, const int* __restrict__ rtype,
    float4* __restrict__ params, const float* __restrict__ temp,
    const float* __restrict__ cr, const float* __restrict__ fuv, float4* __restrict__ perb) {
  const int g = blockIdx.x, tid = threadIdx.x;
  if (g < 1024) {
    // incidence fp32 -> bf16, plain [s][r] layout (B-frags now load direct from L2)
    size_t e = ((size_t)g * 256 + tid) * 8;
    float4 v0 = *(const float4*)(inc + e);
    float4 v1 = *(const float4*)(inc + e + 4);
    bf16x8 o;
    o[0] = (bf16)v0.x; o[1] = (bf16)v0.y; o[2] = (bf16)v0.z; o[3] = (bf16)v0.w;
    o[4] = (bf16)v1.x; o[5] = (bf16)v1.y; o[6] = (bf16)v1.z; o[7] = (bf16)v1.w;
    *(bf16x8*)(incb + e) = o;
    if (g < 32) {
      int r = g * 256 + tid;
      float a = alpha[r], be = beta[r], gm = gam[r];
      int ty = rtype[r];
      int i0 = rm[2 * r], i1 = rm[2 * r + 1];
      float A = a, P = 0.0f, Q = 0.0f;
      if (ty == 0) { P = be; Q = gm; }
      else if (ty == 2) { A = a * expf(-gm); }
      uint32_t bits = (uint32_t)i0 | ((uint32_t)i1 << 10) | ((uint32_t)ty << 20);
      params[r] = make_float4(A, P, Q, __uint_as_float(bits));
    } else if (g < 64) {
      int b = (g - 32) * 256 + tid;
      float T = temp[b];
      perb[b] = make_float4(log2f(T * (1.0f / 300.0f)), 1.4426950408889634f / T, cr[b], fuv[b]);
    }
  } else {
    int gg = g - 1024;
    size_t base = (size_t)gg * 2048 + (size_t)tid * 8;
    *(float4*)(out + base) = make_float4(0.f, 0.f, 0.f, 0.f);
    *(float4*)(out + base + 4) = make_float4(0.f, 0.f, 0.f, 0.f);
  }
}

// ---------- fused flux + GEMM: no inc_lds, B-frags direct from L2, 1 barrier/chunk ----------
__global__ __launch_bounds__(256, 3) void flux_gemm(
    const float* __restrict__ abund, const float4* __restrict__ perb,
    const float4* __restrict__ params, const bf16* __restrict__ incb,
    float* __restrict__ out) {
  __shared__ bf16 ab_lds[257 * 64];      // 32,896 B: [s][b], row 128 B; row 256 = 1.0
  __shared__ bf16 flux_lds[2][64 * BK];  // 8,192 B:  [m][k], 8-blocks XOR-swizzled

  const int tid  = threadIdx.x;
  const int lane = tid & 63;
  const int w    = tid >> 6;
  const int kp   = blockIdx.x & 7;        // == XCD id under round-robin -> L2-local inc strip
  const int m0g  = (blockIdx.x >> 3) * BM;
  const int kstart = kp * KLEN;
  const int r16 = lane & 15, q = lane >> 4;
  const int sw16 = (r16 >> 1) & 3;        // A-frag read swizzle
  const int fsw  = w ^ ((lane >> 1) & 3); // flux write swizzle (m = lane)

  // B-frag pointers: lane reads 8 consecutive k at row n = w*64 + nt*16 + r16
  const bf16* bptr[4];
#pragma unroll
  for (int nt = 0; nt < 4; ++nt)
    bptr[nt] = incb + (size_t)(w * 64 + nt * 16 + r16) * Rn + kstart + q * 8;

  // ---- stage abundances tile transposed [s][b] (once per block) ----
  {
    int bsub = tid >> 2;
    int scol = (tid & 3) * 64;
    const float* rowp = abund + (size_t)(m0g + bsub) * Sn + scol;
#pragma unroll
    for (int j = 0; j < 16; ++j) {
      float4 v = *(const float4*)(rowp + j * 4);
      int s = scol + j * 4;
      ab_lds[(s + 0) * 64 + bsub] = (bf16)v.x;
      ab_lds[(s + 1) * 64 + bsub] = (bf16)v.y;
      ab_lds[(s + 2) * 64 + bsub] = (bf16)v.z;
      ab_lds[(s + 3) * 64 + bsub] = (bf16)v.w;
    }
    if (tid < 64) ab_lds[256 * 64 + tid] = (bf16)1.0f;  // species index S -> 1.0
  }

  float4 pb = perb[m0g + lane];
  const float l2t = pb.x, itv = pb.y, crv = pb.z, fuvv = pb.w;

  // flux tile for chunk c -> flux_lds[buf]; wave w owns k-block w*8, lane owns m=lane
  auto fluxc = [&](int c, int buf) {
    const float4* pw = params + kstart + c * BK + w * 8;
    bf16x8 fv;
#pragma unroll
    for (int j = 0; j < 8; ++j) {
      float4 pr = pw[j];
      uint32_t bits = __float_as_uint(pr.w);
      int i0 = bits & 1023, i1 = (bits >> 10) & 1023, ms = (int)(bits >> 20);
      float a0 = (float)ab_lds[i0 * 64 + lane];
      float a1 = (float)ab_lds[i1 * 64 + lane];
      float v = EXP2F(pr.y * l2t - pr.z * itv);
      float mult = (ms == 1) ? crv : ((ms == 2) ? fuvv : 1.0f);
      fv[j] = (bf16)(pr.x * v * mult * a0 * a1);
    }
    *(bf16x8*)(flux_lds[buf] + lane * BK + fsw * 8) = fv;
  };

  __syncthreads();  // ab_lds ready
  fluxc(0, 0);

  bf16x8 bA[4], bB[4];
#pragma unroll
  for (int nt = 0; nt < 4; ++nt) bA[nt] = *(const bf16x8*)(bptr[nt]);  // chunk-0 B-frags

  f32x4 acc[4][4];
#pragma unroll
  for (int i = 0; i < 4; ++i)
#pragma unroll
    for (int j = 0; j < 4; ++j) acc[i][j] = (f32x4)0.0f;

  __syncthreads();  // flux_lds[0] ready

  // one barrier per chunk; ping-pong register B-frags (2x unroll, no copies)
  auto step = [&](int c, bf16x8 (&bc)[4], bf16x8 (&bn)[4]) {
    const int cur = c & 1;
    bf16x8 af[4];
#pragma unroll
    for (int mt = 0; mt < 4; ++mt)
      af[mt] = *(const bf16x8*)(flux_lds[cur] + (mt * 16 + r16) * BK + (q ^ sw16) * 8);
    if (c + 1 < NC) {
      size_t off = (size_t)(c + 1) * BK;
#pragma unroll
      for (int nt = 0; nt < 4; ++nt) bn[nt] = *(const bf16x8*)(bptr[nt] + off);
      fluxc(c + 1, cur ^ 1);  // gathers+VALU cover the B-load latency
    }
#pragma unroll
    for (int mt = 0; mt < 4; ++mt)
#pragma unroll
      for (int nt = 0; nt < 4; ++nt)
        acc[mt][nt] = __builtin_amdgcn_mfma_f32_16x16x32_bf16(af[mt], bc[nt], acc[mt][nt], 0, 0, 0);
    __syncthreads();
  };

  for (int c = 0; c < NC; c += 2) {
    step(c, bA, bB);
    step(c + 1, bB, bA);
  }

  // epilogue: atomic accumulate the split-K partial (out zeroed in prep)
#pragma unroll
  for (int mt = 0; mt < 4; ++mt)
#pragma unroll
    for (int nt = 0; nt < 4; ++nt) {
      int col = w * 64 + nt * 16 + r16;
      int row = m0g + mt * 16 + q * 4;
#pragma unroll
      for (int rg = 0; rg < 4; ++rg)
        atomicAdd(out + (size_t)(row + rg) * Sn + col, acc[mt][nt][rg]);
    }
}

// ---------- launch ----------
extern "C" void kernel_launch(void* const* d_in, const int* in_sizes, int n_in,
                              void* d_out, int out_size, void* d_ws, size_t ws_size,
                              hipStream_t stream) {
  const float* abund = (const float*)d_in[1];
  const float* temp  = (const float*)d_in[2];
  const float* cr    = (const float*)d_in[3];
  const float* fuv   = (const float*)d_in[4];
  const float* inc   = (const float*)d_in[5];
  const float* alpha = (const float*)d_in[6];
  const float* beta  = (const float*)d_in[7];
  const float* gam   = (const float*)d_in[8];
  const int*   rm    = (const int*)d_in[9];
  const int*   rty   = (const int*)d_in[10];
  float* out = (float*)d_out;

  // ws: params f4[8192] | perb f4[8192] | incb bf16[2M]  (~4.25 MB)
  float4* params = (float4*)d_ws;
  float4* perb   = params + Rn;
  bf16*   incb   = (bf16*)(perb + Bn);

  prep_all<<<2048, 256, 0, stream>>>(inc, incb, out, alpha, beta, gam, rm, rty,
                                     params, temp, cr, fuv, perb);
  flux_gemm<<<(Bn / BM) * KP, 256, 0, stream>>>(abund, perb, params, incb, out);
}

// Round 6
// 310.736 us; speedup vs baseline: 1.1808x; 1.1808x over previous
//
#include <hip/hip_runtime.h>
#include <stdint.h>

typedef __bf16 bf16;
typedef __bf16 bf16x8 __attribute__((ext_vector_type(8)));
typedef float  f32x4  __attribute__((ext_vector_type(4)));

#if __has_builtin(__builtin_amdgcn_exp2f)
#define EXP2F(x) __builtin_amdgcn_exp2f(x)
#else
#define EXP2F(x) exp2f(x)
#endif

constexpr int Bn = 8192, Sn = 256, Rn = 8192;
constexpr int BM = 64, BK = 32, KP = 8;
constexpr int KLEN = Rn / KP;  // 1024
constexpr int NC = KLEN / BK;  // 32 chunks per block

// ---------- prep: params + perb + inc->bf16 frag-packed + zero(out) ----------
// Packed layout: elem[(cg*16 + t)*512 + lane*8 + j] = inc[s = t*16 + (lane&15)]
//                                                        [k = cg*32 + (lane>>4)*8 + j]
// so a wave's B-frag load for (k-chunk cg, s-tile t) is one contiguous 1 KB read.
__global__ __launch_bounds__(256) void prep_all(
    const float* __restrict__ inc, bf16* __restrict__ incb, float* __restrict__ out,
    const float* __restrict__ alpha, const float* __restrict__ beta,
    const float* __restrict__ gam, const int* __restrict__ rm, const int* __restrict__ rtype,
    float4* __restrict__ params, const float* __restrict__ temp,
    const float* __restrict__ cr, const float* __restrict__ fuv, float4* __restrict__ perb) {
  const int g = blockIdx.x, tid = threadIdx.x;
  if (g < 1024) {
    size_t e = ((size_t)g * 256 + tid) * 8;  // [s][r] source elem index
    int s = (int)(e >> 13);
    int kk = (int)(e & 8191);
    float4 v0 = *(const float4*)(inc + e);
    float4 v1 = *(const float4*)(inc + e + 4);
    bf16x8 o;
    o[0] = (bf16)v0.x; o[1] = (bf16)v0.y; o[2] = (bf16)v0.z; o[3] = (bf16)v0.w;
    o[4] = (bf16)v1.x; o[5] = (bf16)v1.y; o[6] = (bf16)v1.z; o[7] = (bf16)v1.w;
    int c = kk >> 5, q = (kk >> 3) & 3, t = s >> 4, r16 = s & 15;
    size_t dst = ((size_t)(c * 16 + t) << 9) + (size_t)(q * 16 + r16) * 8;
    *(bf16x8*)(incb + dst) = o;
    if (g < 32) {
      int r = g * 256 + tid;
      float a = alpha[r], be = beta[r], gm = gam[r];
      int ty = rtype[r];
      int i0 = rm[2 * r], i1 = rm[2 * r + 1];
      float A = a, P = 0.0f, Q = 0.0f;
      if (ty == 0) { P = be; Q = gm; }
      else if (ty == 2) { A = a * expf(-gm); }
      uint32_t bits = (uint32_t)i0 | ((uint32_t)i1 << 10) | ((uint32_t)ty << 20);
      params[r] = make_float4(A, P, Q, __uint_as_float(bits));
    } else if (g < 64) {
      int b = (g - 32) * 256 + tid;
      float T = temp[b];
      perb[b] = make_float4(log2f(T * (1.0f / 300.0f)), 1.4426950408889634f / T, cr[b], fuv[b]);
    }
  } else {
    int gg = g - 1024;
    size_t base = (size_t)gg * 2048 + (size_t)tid * 8;
    *(float4*)(out + base) = make_float4(0.f, 0.f, 0.f, 0.f);
    *(float4*)(out + base + 4) = make_float4(0.f, 0.f, 0.f, 0.f);
  }
}

// ---------- fused flux + GEMM: B-frags coalesced from L2, 1 barrier/chunk ----------
__global__ __launch_bounds__(256, 3) void flux_gemm(
    const float* __restrict__ abund, const float4* __restrict__ perb,
    const float4* __restrict__ params, const bf16* __restrict__ incb,
    float* __restrict__ out) {
  __shared__ bf16 ab_lds[257 * 64];      // 32,896 B: [s][b]
  __shared__ bf16 flux_lds[2][64 * BK];  // 8,192 B:  [m][k], 8-blocks XOR-swizzled

  const int tid  = threadIdx.x;
  const int lane = tid & 63;
  const int w    = tid >> 6;
  const int kp   = blockIdx.x & 7;   // == XCD id under round-robin -> L2-local B strip
  const int jb   = blockIdx.x >> 3;  // 0..127
  // stagger: the 8 kp-writers of one m-tile are >=128 block-indices apart
  const int m0g  = ((jb + (kp << 4)) & 127) * BM;
  const int kstart = kp * KLEN;
  const int r16 = lane & 15, q = lane >> 4;
  const int sw16 = (r16 >> 1) & 3;         // A-frag read swizzle
  const int fsw  = w ^ ((lane >> 1) & 3);  // flux write swizzle (m = lane)

  // B-frag pointers into frag-packed incb: chunk cg, tile t=w*4+nt ->
  // 1 KB contiguous, lane reads 16B at lane*16
  const bf16* bptr[4];
#pragma unroll
  for (int nt = 0; nt < 4; ++nt)
    bptr[nt] = incb + (((size_t)kp * NC * 16 + w * 4 + nt) << 9) + (size_t)lane * 8;
  constexpr size_t CSTRIDE = 16 << 9;  // 8192 elems per chunk

  // ---- stage abundances tile transposed [s][b] (once per block) ----
  {
    int bsub = tid >> 2;
    int scol = (tid & 3) * 64;
    const float* rowp = abund + (size_t)(m0g + bsub) * Sn + scol;
#pragma unroll
    for (int j = 0; j < 16; ++j) {
      float4 v = *(const float4*)(rowp + j * 4);
      int s = scol + j * 4;
      ab_lds[(s + 0) * 64 + bsub] = (bf16)v.x;
      ab_lds[(s + 1) * 64 + bsub] = (bf16)v.y;
      ab_lds[(s + 2) * 64 + bsub] = (bf16)v.z;
      ab_lds[(s + 3) * 64 + bsub] = (bf16)v.w;
    }
    if (tid < 64) ab_lds[256 * 64 + tid] = (bf16)1.0f;  // species index S -> 1.0
  }

  float4 pb = perb[m0g + lane];
  const float l2t = pb.x, itv = pb.y, crv = pb.z, fuvv = pb.w;

  // flux tile for chunk c -> flux_lds[buf]; wave w owns k-block w*8, lane owns m=lane
  auto fluxc = [&](int c, int buf) {
    const float4* pw = params + kstart + c * BK + w * 8;
    bf16x8 fv;
#pragma unroll
    for (int j = 0; j < 8; ++j) {
      float4 pr = pw[j];
      uint32_t bits = __float_as_uint(pr.w);
      int i0 = bits & 1023, i1 = (bits >> 10) & 1023, ms = (int)(bits >> 20);
      float a0 = (float)ab_lds[i0 * 64 + lane];
      float a1 = (float)ab_lds[i1 * 64 + lane];
      float v = EXP2F(pr.y * l2t - pr.z * itv);
      float mult = (ms == 1) ? crv : ((ms == 2) ? fuvv : 1.0f);
      fv[j] = (bf16)(pr.x * v * mult * a0 * a1);
    }
    *(bf16x8*)(flux_lds[buf] + lane * BK + fsw * 8) = fv;
  };

  __syncthreads();  // ab_lds ready
  fluxc(0, 0);

  bf16x8 bA[4], bB[4];
#pragma unroll
  for (int nt = 0; nt < 4; ++nt) bA[nt] = *(const bf16x8*)(bptr[nt]);  // chunk-0 B-frags

  f32x4 acc[4][4];
#pragma unroll
  for (int i = 0; i < 4; ++i)
#pragma unroll
    for (int j = 0; j < 4; ++j) acc[i][j] = (f32x4)0.0f;

  __syncthreads();  // flux_lds[0] ready

  auto step = [&](int c, bf16x8 (&bc)[4], bf16x8 (&bn)[4]) {
    const int cur = c & 1;
    bf16x8 af[4];
#pragma unroll
    for (int mt = 0; mt < 4; ++mt)
      af[mt] = *(const bf16x8*)(flux_lds[cur] + (mt * 16 + r16) * BK + (q ^ sw16) * 8);
    if (c + 1 < NC) {
      size_t off = (size_t)(c + 1) * CSTRIDE;
#pragma unroll
      for (int nt = 0; nt < 4; ++nt) bn[nt] = *(const bf16x8*)(bptr[nt] + off);
      fluxc(c + 1, cur ^ 1);  // gathers+VALU cover the B-load latency
    }
#pragma unroll
    for (int mt = 0; mt < 4; ++mt)
#pragma unroll
      for (int nt = 0; nt < 4; ++nt)
        acc[mt][nt] = __builtin_amdgcn_mfma_f32_16x16x32_bf16(af[mt], bc[nt], acc[mt][nt], 0, 0, 0);
    __syncthreads();
  };

  for (int c = 0; c < NC; c += 2) {
    step(c, bA, bB);
    step(c + 1, bB, bA);
  }

  // epilogue: staggered atomic accumulate (out zeroed in prep)
#pragma unroll
  for (int mt = 0; mt < 4; ++mt)
#pragma unroll
    for (int nt = 0; nt < 4; ++nt) {
      int col = w * 64 + nt * 16 + r16;
      int row = m0g + mt * 16 + q * 4;
#pragma unroll
      for (int rg = 0; rg < 4; ++rg)
        atomicAdd(out + (size_t)(row + rg) * Sn + col, acc[mt][nt][rg]);
    }
}

// ---------- launch ----------
extern "C" void kernel_launch(void* const* d_in, const int* in_sizes, int n_in,
                              void* d_out, int out_size, void* d_ws, size_t ws_size,
                              hipStream_t stream) {
  const float* abund = (const float*)d_in[1];
  const float* temp  = (const float*)d_in[2];
  const float* cr    = (const float*)d_in[3];
  const float* fuv   = (const float*)d_in[4];
  const float* inc   = (const float*)d_in[5];
  const float* alpha = (const float*)d_in[6];
  const float* beta  = (const float*)d_in[7];
  const float* gam   = (const float*)d_in[8];
  const int*   rm    = (const int*)d_in[9];
  const int*   rty   = (const int*)d_in[10];
  float* out = (float*)d_out;

  // ws: params f4[8192] | perb f4[8192] | incb bf16[2M]  (~4.25 MB)
  float4* params = (float4*)d_ws;
  float4* perb   = params + Rn;
  bf16*   incb   = (bf16*)(perb + Bn);

  prep_all<<<2048, 256, 0, stream>>>(inc, incb, out, alpha, beta, gam, rm, rty,
                                     params, temp, cr, fuv, perb);
  flux_gemm<<<(Bn / BM) * KP, 256, 0, stream>>>(abund, perb, params, incb, out);
}

// Round 7
// 310.313 us; speedup vs baseline: 1.1824x; 1.0014x over previous
//
#include <hip/hip_runtime.h>
#include <stdint.h>

typedef __bf16 bf16;
typedef __bf16 bf16x4 __attribute__((ext_vector_type(4)));
typedef __bf16 bf16x8 __attribute__((ext_vector_type(8)));
typedef float  f32x4  __attribute__((ext_vector_type(4)));

#if __has_builtin(__builtin_amdgcn_exp2f)
#define EXP2F(x) __builtin_amdgcn_exp2f(x)
#else
#define EXP2F(x) exp2f(x)
#endif

constexpr int Bn = 8192, Sn = 256, Rn = 8192;
constexpr int BM = 64, BK = 32, KP = 8;
constexpr int KLEN = Rn / KP;  // 1024
constexpr int NC = KLEN / BK;  // 32 chunks per block
constexpr size_t PSTRIDE = (size_t)Bn * Sn;  // partial elems per kp (2M)

// ---------- prep: params + perb + inc->bf16 frag-packed ----------
// Packed: elem[(cg*16 + t)*512 + lane*8 + j] = inc[s = t*16 + (lane&15)][k = cg*32 + (lane>>4)*8 + j]
// -> a wave's B-frag load for (chunk cg, s-tile t) is one contiguous 1 KB read.
__global__ __launch_bounds__(256) void prep_all(
    const float* __restrict__ inc, bf16* __restrict__ incb,
    const float* __restrict__ alpha, const float* __restrict__ beta,
    const float* __restrict__ gam, const int* __restrict__ rm, const int* __restrict__ rtype,
    float4* __restrict__ params, const float* __restrict__ temp,
    const float* __restrict__ cr, const float* __restrict__ fuv, float4* __restrict__ perb) {
  const int g = blockIdx.x, tid = threadIdx.x;
  size_t e = ((size_t)g * 256 + tid) * 8;  // [s][r] source elem index
  int s = (int)(e >> 13);
  int kk = (int)(e & 8191);
  float4 v0 = *(const float4*)(inc + e);
  float4 v1 = *(const float4*)(inc + e + 4);
  bf16x8 o;
  o[0] = (bf16)v0.x; o[1] = (bf16)v0.y; o[2] = (bf16)v0.z; o[3] = (bf16)v0.w;
  o[4] = (bf16)v1.x; o[5] = (bf16)v1.y; o[6] = (bf16)v1.z; o[7] = (bf16)v1.w;
  int c = kk >> 5, q = (kk >> 3) & 3, t = s >> 4, r16 = s & 15;
  size_t dst = ((size_t)(c * 16 + t) << 9) + (size_t)(q * 16 + r16) * 8;
  *(bf16x8*)(incb + dst) = o;
  if (g < 32) {
    int r = g * 256 + tid;
    float a = alpha[r], be = beta[r], gm = gam[r];
    int ty = rtype[r];
    int i0 = rm[2 * r], i1 = rm[2 * r + 1];
    float A = a, P = 0.0f, Q = 0.0f;
    if (ty == 0) { P = be; Q = gm; }
    else if (ty == 2) { A = a * expf(-gm); }
    uint32_t bits = (uint32_t)i0 | ((uint32_t)i1 << 10) | ((uint32_t)ty << 20);
    params[r] = make_float4(A, P, Q, __uint_as_float(bits));
  } else if (g < 64) {
    int b = (g - 32) * 256 + tid;
    float T = temp[b];
    perb[b] = make_float4(log2f(T * (1.0f / 300.0f)), 1.4426950408889634f / T, cr[b], fuv[b]);
  }
}

// ---------- fused flux + GEMM: plain bf16 partial stores (no atomics) ----------
__global__ __launch_bounds__(256, 3) void flux_gemm(
    const float* __restrict__ abund, const float4* __restrict__ perb,
    const float4* __restrict__ params, const bf16* __restrict__ incb,
    bf16* __restrict__ partial) {
  __shared__ bf16 ab_lds[257 * 64];      // 32,896 B: [s][b]
  __shared__ bf16 flux_lds[2][64 * BK];  // 8,192 B:  [m][k], 8-blocks XOR-swizzled

  const int tid  = threadIdx.x;
  const int lane = tid & 63;
  const int w    = tid >> 6;
  const int kp   = blockIdx.x & 7;   // == XCD id -> L2-local B strip
  const int jb   = blockIdx.x >> 3;  // m-tile 0..127
  const int m0g  = jb * BM;
  const int kstart = kp * KLEN;
  const int r16 = lane & 15, q = lane >> 4;
  const int sw16 = (r16 >> 1) & 3;         // A-frag read swizzle
  const int fsw  = w ^ ((lane >> 1) & 3);  // flux write swizzle (m = lane)

  // B-frag pointers into frag-packed incb
  const bf16* bptr[4];
#pragma unroll
  for (int nt = 0; nt < 4; ++nt)
    bptr[nt] = incb + (((size_t)kp * NC * 16 + w * 4 + nt) << 9) + (size_t)lane * 8;
  constexpr size_t CSTRIDE = 16 << 9;  // 8192 elems per chunk

  // ---- stage abundances tile transposed [s][b] (once per block) ----
  {
    int bsub = tid >> 2;
    int scol = (tid & 3) * 64;
    const float* rowp = abund + (size_t)(m0g + bsub) * Sn + scol;
#pragma unroll
    for (int j = 0; j < 16; ++j) {
      float4 v = *(const float4*)(rowp + j * 4);
      int s = scol + j * 4;
      ab_lds[(s + 0) * 64 + bsub] = (bf16)v.x;
      ab_lds[(s + 1) * 64 + bsub] = (bf16)v.y;
      ab_lds[(s + 2) * 64 + bsub] = (bf16)v.z;
      ab_lds[(s + 3) * 64 + bsub] = (bf16)v.w;
    }
    if (tid < 64) ab_lds[256 * 64 + tid] = (bf16)1.0f;  // species index S -> 1.0
  }

  float4 pb = perb[m0g + lane];
  const float l2t = pb.x, itv = pb.y, crv = pb.z, fuvv = pb.w;

  auto fluxc = [&](int c, int buf) {
    const float4* pw = params + kstart + c * BK + w * 8;
    bf16x8 fv;
#pragma unroll
    for (int j = 0; j < 8; ++j) {
      float4 pr = pw[j];
      uint32_t bits = __float_as_uint(pr.w);
      int i0 = bits & 1023, i1 = (bits >> 10) & 1023, ms = (int)(bits >> 20);
      float a0 = (float)ab_lds[i0 * 64 + lane];
      float a1 = (float)ab_lds[i1 * 64 + lane];
      float v = EXP2F(pr.y * l2t - pr.z * itv);
      float mult = (ms == 1) ? crv : ((ms == 2) ? fuvv : 1.0f);
      fv[j] = (bf16)(pr.x * v * mult * a0 * a1);
    }
    *(bf16x8*)(flux_lds[buf] + lane * BK + fsw * 8) = fv;
  };

  __syncthreads();  // ab_lds ready
  fluxc(0, 0);

  bf16x8 bA[4], bB[4];
#pragma unroll
  for (int nt = 0; nt < 4; ++nt) bA[nt] = *(const bf16x8*)(bptr[nt]);

  f32x4 acc[4][4];
#pragma unroll
  for (int i = 0; i < 4; ++i)
#pragma unroll
    for (int j = 0; j < 4; ++j) acc[i][j] = (f32x4)0.0f;

  __syncthreads();  // flux_lds[0] ready

  auto step = [&](int c, bf16x8 (&bc)[4], bf16x8 (&bn)[4]) {
    const int cur = c & 1;
    bf16x8 af[4];
#pragma unroll
    for (int mt = 0; mt < 4; ++mt)
      af[mt] = *(const bf16x8*)(flux_lds[cur] + (mt * 16 + r16) * BK + (q ^ sw16) * 8);
    if (c + 1 < NC) {
      size_t off = (size_t)(c + 1) * CSTRIDE;
#pragma unroll
      for (int nt = 0; nt < 4; ++nt) bn[nt] = *(const bf16x8*)(bptr[nt] + off);
      fluxc(c + 1, cur ^ 1);
    }
#pragma unroll
    for (int mt = 0; mt < 4; ++mt)
#pragma unroll
      for (int nt = 0; nt < 4; ++nt)
        acc[mt][nt] = __builtin_amdgcn_mfma_f32_16x16x32_bf16(af[mt], bc[nt], acc[mt][nt], 0, 0, 0);
    __syncthreads();
  };

  for (int c = 0; c < NC; c += 2) {
    step(c, bA, bB);
    step(c + 1, bB, bA);
  }

  // epilogue: bf16 partials in C-fragment order, lane-contiguous (512 B per wave per mn)
  // layout: partial[kp][jb][w][mn][lane*4 + rg]
  bf16* pp = partial + (((size_t)kp * 128 + jb) * 4 + w) * (16 * 256) + (size_t)lane * 4;
#pragma unroll
  for (int mt = 0; mt < 4; ++mt)
#pragma unroll
    for (int nt = 0; nt < 4; ++nt) {
      bf16x4 v;
#pragma unroll
      for (int rg = 0; rg < 4; ++rg) v[rg] = (bf16)acc[mt][nt][rg];
      *(bf16x4*)(pp + (mt * 4 + nt) * 256) = v;
    }
}

// ---------- split-K reduce: sum 8 bf16 partials -> fp32 out ----------
__global__ __launch_bounds__(256) void reduce_k(const bf16* __restrict__ partial,
                                               float* __restrict__ out) {
  // u indexes (jb, w, mn, lane): u = ((jb*4 + w)*16 + mn)*64 + lane
  int u = blockIdx.x * 256 + threadIdx.x;
  int lane = u & 63;
  int mn = (u >> 6) & 15;
  int w  = (u >> 10) & 3;
  int jb = u >> 12;
  const bf16* p = partial + (size_t)u * 4;
  float s0 = 0.f, s1 = 0.f, s2 = 0.f, s3 = 0.f;
#pragma unroll
  for (int kp = 0; kp < KP; ++kp) {
    bf16x4 v = *(const bf16x4*)(p + (size_t)kp * PSTRIDE);
    s0 += (float)v[0]; s1 += (float)v[1]; s2 += (float)v[2]; s3 += (float)v[3];
  }
  int row = jb * 64 + (mn >> 2) * 16 + (lane >> 4) * 4;
  int col = w * 64 + (mn & 3) * 16 + (lane & 15);
  float* o = out + (size_t)row * Sn + col;
  o[0 * Sn] = s0; o[1 * Sn] = s1; o[2 * Sn] = s2; o[3 * Sn] = s3;
}

// ---------- launch ----------
extern "C" void kernel_launch(void* const* d_in, const int* in_sizes, int n_in,
                              void* d_out, int out_size, void* d_ws, size_t ws_size,
                              hipStream_t stream) {
  const float* abund = (const float*)d_in[1];
  const float* temp  = (const float*)d_in[2];
  const float* cr    = (const float*)d_in[3];
  const float* fuv   = (const float*)d_in[4];
  const float* inc   = (const float*)d_in[5];
  const float* alpha = (const float*)d_in[6];
  const float* beta  = (const float*)d_in[7];
  const float* gam   = (const float*)d_in[8];
  const int*   rm    = (const int*)d_in[9];
  const int*   rty   = (const int*)d_in[10];
  float* out = (float*)d_out;

  // ws: params f4[8192] | perb f4[8192] | incb bf16[2M] | partial bf16[8*2M]  (~36.4 MB)
  float4* params  = (float4*)d_ws;
  float4* perb    = params + Rn;
  bf16*   incb    = (bf16*)(perb + Bn);
  bf16*   partial = incb + (size_t)Sn * Rn;

  prep_all<<<1024, 256, 0, stream>>>(inc, incb, alpha, beta, gam, rm, rty,
                                     params, temp, cr, fuv, perb);
  flux_gemm<<<(Bn / BM) * KP, 256, 0, stream>>>(abund, perb, params, incb, partial);
  reduce_k<<<(Bn * Sn / 4) / 256, 256, 0, stream>>>(partial, out);
}

// Round 8
// 205.507 us; speedup vs baseline: 1.7855x; 1.5100x over previous
//
#include <hip/hip_runtime.h>
#include <stdint.h>

typedef __bf16 bf16;
typedef __bf16 bf16x4 __attribute__((ext_vector_type(4)));
typedef __bf16 bf16x8 __attribute__((ext_vector_type(8)));
typedef float  f32x4  __attribute__((ext_vector_type(4)));

#if __has_builtin(__builtin_amdgcn_exp2f)
#define EXP2F(x) __builtin_amdgcn_exp2f(x)
#else
#define EXP2F(x) exp2f(x)
#endif

constexpr int Bn = 8192, Sn = 256, Rn = 8192;
constexpr int BM = 64, BK = 32, KP = 4;
constexpr int KLEN = Rn / KP;  // 2048
constexpr int NC = KLEN / BK;  // 64 chunks per block
constexpr size_t PSTRIDE = (size_t)Bn * Sn;  // partial elems per kp (2M)

// ---------- prep: params + perb + inc->bf16 frag-packed ----------
// Packed: elem[(cg*16 + t)*512 + (q*16+r16)*8 + j] = inc[s = t*16 + r16][k = cg*32 + q*8 + j]
// -> a wave's B-frag load for (global chunk cg, s-tile t) is one contiguous 1 KB read.
__global__ __launch_bounds__(256) void prep_all(
    const float* __restrict__ inc, bf16* __restrict__ incb,
    const float* __restrict__ alpha, const float* __restrict__ beta,
    const float* __restrict__ gam, const int* __restrict__ rm, const int* __restrict__ rtype,
    float4* __restrict__ params, const float* __restrict__ temp,
    const float* __restrict__ cr, const float* __restrict__ fuv, float4* __restrict__ perb) {
  const int g = blockIdx.x, tid = threadIdx.x;
  size_t e = ((size_t)g * 256 + tid) * 8;  // flat [s][r] elem index
  int s = (int)(e >> 13);
  int kk = (int)(e & 8191);
  float4 v0 = *(const float4*)(inc + e);
  float4 v1 = *(const float4*)(inc + e + 4);
  bf16x8 o;
  o[0] = (bf16)v0.x; o[1] = (bf16)v0.y; o[2] = (bf16)v0.z; o[3] = (bf16)v0.w;
  o[4] = (bf16)v1.x; o[5] = (bf16)v1.y; o[6] = (bf16)v1.z; o[7] = (bf16)v1.w;
  int c = kk >> 5, q = (kk >> 3) & 3, t = s >> 4, r16 = s & 15;
  size_t dst = ((size_t)(c * 16 + t) << 9) + (size_t)(q * 16 + r16) * 8;
  *(bf16x8*)(incb + dst) = o;
  if (g < 32) {
    int r = g * 256 + tid;
    float a = alpha[r], be = beta[r], gm = gam[r];
    int ty = rtype[r];
    int i0 = rm[2 * r], i1 = rm[2 * r + 1];
    float A = a, P = 0.0f, Q = 0.0f;
    if (ty == 0) { P = be; Q = gm; }
    else if (ty == 2) { A = a * expf(-gm); }
    uint32_t bits = (uint32_t)i0 | ((uint32_t)i1 << 10) | ((uint32_t)ty << 20);
    params[r] = make_float4(A, P, Q, __uint_as_float(bits));
  } else if (g < 64) {
    int b = (g - 32) * 256 + tid;
    float T = temp[b];
    perb[b] = make_float4(log2f(T * (1.0f / 300.0f)), 1.4426950408889634f / T, cr[b], fuv[b]);
  }
}

// ---------- fused flux + GEMM: direct B-frags, flux dbuf, 1 barrier/chunk ----------
// bounds(256,2): 256-VGPR cap -> no scratch spills (the R5-R7 bounds-3 regression).
__global__ __launch_bounds__(256, 2) void flux_gemm(
    const float* __restrict__ abund, const float4* __restrict__ perb,
    const float4* __restrict__ params, const bf16* __restrict__ incb,
    bf16* __restrict__ partial) {
  __shared__ bf16 ab_lds[257 * 64];      // 32,896 B: [s][b]
  __shared__ bf16 flux_lds[2][64 * BK];  // 8,192 B:  [m][k], 8-blocks XOR-swizzled

  const int tid  = threadIdx.x;
  const int lane = tid & 63;
  const int w    = tid >> 6;
  const int kp   = blockIdx.x & 3;   // k-partition
  const int jb   = blockIdx.x >> 2;  // m-tile 0..127
  const int m0g  = jb * BM;
  const int kstart = kp * KLEN;
  const int r16 = lane & 15, q = lane >> 4;
  const int sw16 = (r16 >> 1) & 3;         // A-frag read swizzle
  const int fsw  = w ^ ((lane >> 1) & 3);  // flux write swizzle (m = lane)

  // B-frag base pointers into frag-packed incb (global chunk = kp*NC + c)
  const bf16* bptr[4];
#pragma unroll
  for (int nt = 0; nt < 4; ++nt)
    bptr[nt] = incb + (((size_t)kp * NC * 16 + w * 4 + nt) << 9) + (size_t)lane * 8;
  constexpr size_t CSTRIDE = 16 << 9;  // 8192 elems per chunk

  // ---- stage abundances tile transposed [s][b] (once per block) ----
  {
    int bsub = tid >> 2;
    int scol = (tid & 3) * 64;
    const float* rowp = abund + (size_t)(m0g + bsub) * Sn + scol;
#pragma unroll
    for (int j = 0; j < 16; ++j) {
      float4 v = *(const float4*)(rowp + j * 4);
      int s = scol + j * 4;
      ab_lds[(s + 0) * 64 + bsub] = (bf16)v.x;
      ab_lds[(s + 1) * 64 + bsub] = (bf16)v.y;
      ab_lds[(s + 2) * 64 + bsub] = (bf16)v.z;
      ab_lds[(s + 3) * 64 + bsub] = (bf16)v.w;
    }
    if (tid < 64) ab_lds[256 * 64 + tid] = (bf16)1.0f;  // species index S -> 1.0
  }

  float4 pb = perb[m0g + lane];
  const float l2t = pb.x, itv = pb.y, crv = pb.z, fuvv = pb.w;

  // flux tile for chunk c -> flux_lds[buf]; wave w owns k-block w*8, lane owns m=lane
  auto fluxc = [&](int c, int buf) {
    const float4* pw = params + kstart + c * BK + w * 8;
    bf16x8 fv;
#pragma unroll
    for (int j = 0; j < 8; ++j) {
      float4 pr = pw[j];
      uint32_t bits = __float_as_uint(pr.w);
      int i0 = bits & 1023, i1 = (bits >> 10) & 1023, ms = (int)(bits >> 20);
      float a0 = (float)ab_lds[i0 * 64 + lane];
      float a1 = (float)ab_lds[i1 * 64 + lane];
      float v = EXP2F(pr.y * l2t - pr.z * itv);
      float mult = (ms == 1) ? crv : ((ms == 2) ? fuvv : 1.0f);
      fv[j] = (bf16)(pr.x * v * mult * a0 * a1);
    }
    *(bf16x8*)(flux_lds[buf] + lane * BK + fsw * 8) = fv;
  };

  __syncthreads();  // ab_lds ready
  fluxc(0, 0);

  f32x4 acc[4][4];
#pragma unroll
  for (int i = 0; i < 4; ++i)
#pragma unroll
    for (int j = 0; j < 4; ++j) acc[i][j] = (f32x4)0.0f;

  __syncthreads();  // flux_lds[0] ready

  for (int c = 0; c < NC; ++c) {
    const int cur = c & 1;
    // B-frags for THIS chunk: issue first, ~260 VALU cycles of flux cover L2 latency
    bf16x8 bfr[4];
    {
      size_t off = (size_t)c * CSTRIDE;
#pragma unroll
      for (int nt = 0; nt < 4; ++nt) bfr[nt] = *(const bf16x8*)(bptr[nt] + off);
    }
    bf16x8 af[4];
#pragma unroll
    for (int mt = 0; mt < 4; ++mt)
      af[mt] = *(const bf16x8*)(flux_lds[cur] + (mt * 16 + r16) * BK + (q ^ sw16) * 8);
    if (c + 1 < NC) fluxc(c + 1, cur ^ 1);  // overlaps with MFMA below
#pragma unroll
    for (int mt = 0; mt < 4; ++mt)
#pragma unroll
      for (int nt = 0; nt < 4; ++nt)
        acc[mt][nt] = __builtin_amdgcn_mfma_f32_16x16x32_bf16(af[mt], bfr[nt], acc[mt][nt], 0, 0, 0);
    __syncthreads();
  }

  // epilogue: bf16 partials in C-fragment order, lane-contiguous
  // layout: partial[kp][jb][w][mn][lane*4 + rg]
  bf16* pp = partial + (((size_t)kp * 128 + jb) * 4 + w) * (16 * 256) + (size_t)lane * 4;
#pragma unroll
  for (int mt = 0; mt < 4; ++mt)
#pragma unroll
    for (int nt = 0; nt < 4; ++nt) {
      bf16x4 v;
#pragma unroll
      for (int rg = 0; rg < 4; ++rg) v[rg] = (bf16)acc[mt][nt][rg];
      *(bf16x4*)(pp + (mt * 4 + nt) * 256) = v;
    }
}

// ---------- split-K reduce: sum KP bf16 partials -> fp32 out ----------
__global__ __launch_bounds__(256) void reduce_k(const bf16* __restrict__ partial,
                                               float* __restrict__ out) {
  // u indexes (jb, w, mn, lane): u = ((jb*4 + w)*16 + mn)*64 + lane
  int u = blockIdx.x * 256 + threadIdx.x;
  int lane = u & 63;
  int mn = (u >> 6) & 15;
  int w  = (u >> 10) & 3;
  int jb = u >> 12;
  const bf16* p = partial + (size_t)u * 4;
  float s0 = 0.f, s1 = 0.f, s2 = 0.f, s3 = 0.f;
#pragma unroll
  for (int kp = 0; kp < KP; ++kp) {
    bf16x4 v = *(const bf16x4*)(p + (size_t)kp * PSTRIDE);
    s0 += (float)v[0]; s1 += (float)v[1]; s2 += (float)v[2]; s3 += (float)v[3];
  }
  int row = jb * 64 + (mn >> 2) * 16 + (lane >> 4) * 4;
  int col = w * 64 + (mn & 3) * 16 + (lane & 15);
  float* o = out + (size_t)row * Sn + col;
  o[0 * Sn] = s0; o[1 * Sn] = s1; o[2 * Sn] = s2; o[3 * Sn] = s3;
}

// ---------- launch ----------
extern "C" void kernel_launch(void* const* d_in, const int* in_sizes, int n_in,
                              void* d_out, int out_size, void* d_ws, size_t ws_size,
                              hipStream_t stream) {
  const float* abund = (const float*)d_in[1];
  const float* temp  = (const float*)d_in[2];
  const float* cr    = (const float*)d_in[3];
  const float* fuv   = (const float*)d_in[4];
  const float* inc   = (const float*)d_in[5];
  const float* alpha = (const float*)d_in[6];
  const float* beta  = (const float*)d_in[7];
  const float* gam   = (const float*)d_in[8];
  const int*   rm    = (const int*)d_in[9];
  const int*   rty   = (const int*)d_in[10];
  float* out = (float*)d_out;

  // ws: params f4[8192] | perb f4[8192] | incb bf16[2M] | partial bf16[4*2M]  (~20.4 MB)
  float4* params  = (float4*)d_ws;
  float4* perb    = params + Rn;
  bf16*   incb    = (bf16*)(perb + Bn);
  bf16*   partial = incb + (size_t)Sn * Rn;

  prep_all<<<1024, 256, 0, stream>>>(inc, incb, alpha, beta, gam, rm, rty,
                                     params, temp, cr, fuv, perb);
  flux_gemm<<<(Bn / BM) * KP, 256, 0, stream>>>(abund, perb, params, incb, partial);
  reduce_k<<<(Bn * Sn / 4) / 256, 256, 0, stream>>>(partial, out);
}